// Round 2
// baseline (510.468 us; speedup 1.0000x reference)
//
#include <hip/hip_runtime.h>

// ---------------------------------------------------------------------------
// Naive3DConvEncoder: scatter -> conv1(1->16) -> conv2(16->32) -> conv3(32->64) -> FC
// All fp32. B=32, N=16384, G=64, LATENT=128.
// ws layout:
//   grid_u8 : offset 0,          32*64^3 bytes            =  8,388,608
//   conv1   : offset 8,388,608,  32*16*32^3 floats        = 67,108,864 B
//   conv2   : offset 75,497,472, 32*32*16^3 floats        = 16,777,216 B
//   feat    : offset 92,274,688, 32*64*8^3 floats         =  4,194,304 B
// ---------------------------------------------------------------------------

__global__ void k_scatter(const float* __restrict__ coords,
                          unsigned char* __restrict__ grid) {
    int i = blockIdx.x * 256 + threadIdx.x;          // 524288 threads
    float cx = coords[3 * i + 0];
    float cy = coords[3 * i + 1];
    float cz = coords[3 * i + 2];
    int ix = (int)((cx + 1.0f) * 0.5f * 63.0f);      // trunc like astype(int32)
    int iy = (int)((cy + 1.0f) * 0.5f * 63.0f);
    int iz = (int)((cz + 1.0f) * 0.5f * 63.0f);
    ix = min(max(ix, 0), 63);
    iy = min(max(iy, 0), 63);
    iz = min(max(iz, 0), 63);
    int b = i >> 14;                                 // N = 16384
    grid[((b * 64 + iz) * 64 + iy) * 64 + ix] = 1;   // duplicates write same value
}

// conv1: input binary grid (B,64,64,64) u8 -> out (B,16,32,32,32) fp32, relu
__global__ void k_conv1(const unsigned char* __restrict__ grid,
                        const float* __restrict__ w1,
                        const float* __restrict__ b1,
                        float* __restrict__ out) {
    int idx = blockIdx.x * 256 + threadIdx.x;        // 1,048,576 threads
    int x = idx & 31, y = (idx >> 5) & 31, z = (idx >> 10) & 31, b = idx >> 15;
    const unsigned char* g = grid + b * 262144;
    float in27[27];
#pragma unroll
    for (int kz = 0; kz < 3; ++kz)
#pragma unroll
        for (int ky = 0; ky < 3; ++ky)
#pragma unroll
            for (int kx = 0; kx < 3; ++kx) {
                int iz = 2 * z + kz - 1, iy = 2 * y + ky - 1, ix = 2 * x + kx - 1;
                bool ok = ((unsigned)iz < 64u) & ((unsigned)iy < 64u) & ((unsigned)ix < 64u);
                in27[kz * 9 + ky * 3 + kx] = ok ? (float)g[(iz * 64 + iy) * 64 + ix] : 0.0f;
            }
    float* o = out + b * (16 * 32768) + (z * 1024 + y * 32 + x);
#pragma unroll
    for (int oc = 0; oc < 16; ++oc) {
        float acc = b1[oc];
#pragma unroll
        for (int k = 0; k < 27; ++k) acc = fmaf(w1[oc * 27 + k], in27[k], acc);
        o[oc * 32768] = fmaxf(acc, 0.0f);
    }
}

// conv2: (B,16,32^3) -> (B,32,16^3), relu. Thread per (b,z,y,x), 32 oc accums.
// Weights read via wave-uniform GLOBAL addresses (expect s_load scalarization).
__global__ void k_conv2(const float* __restrict__ in,
                        const float* __restrict__ w2,
                        const float* __restrict__ b2,
                        float* __restrict__ out) {
    int idx = blockIdx.x * 256 + threadIdx.x;        // 131,072 threads
    int x = idx & 15, y = (idx >> 4) & 15, z = (idx >> 8) & 15, b = idx >> 12;
    const float* ib = in + b * 16 * 32768;
    float acc[32];
#pragma unroll
    for (int oc = 0; oc < 32; ++oc) acc[oc] = b2[oc];
    for (int c = 0; c < 16; ++c) {
        float in27[27];
#pragma unroll
        for (int kz = 0; kz < 3; ++kz)
#pragma unroll
            for (int ky = 0; ky < 3; ++ky)
#pragma unroll
                for (int kx = 0; kx < 3; ++kx) {
                    int iz = 2 * z + kz - 1, iy = 2 * y + ky - 1, ix = 2 * x + kx - 1;
                    bool ok = ((unsigned)iz < 32u) & ((unsigned)iy < 32u) & ((unsigned)ix < 32u);
                    in27[kz * 9 + ky * 3 + kx] =
                        ok ? ib[c * 32768 + iz * 1024 + iy * 32 + ix] : 0.0f;
                }
#pragma unroll
        for (int k = 0; k < 27; ++k) {
            float v = in27[k];
#pragma unroll
            for (int oc = 0; oc < 32; ++oc)
                acc[oc] = fmaf(w2[(oc * 16 + c) * 27 + k], v, acc[oc]);
        }
    }
    float* o = out + b * 32 * 4096 + (z * 256 + y * 16 + x);
#pragma unroll
    for (int oc = 0; oc < 32; ++oc) o[oc * 4096] = fmaxf(acc[oc], 0.0f);
}

// conv3: (B,32,16^3) -> (B,64,8^3), relu. Block = (b, ocg of 8 oc); LDS weights
// transposed [c*27+k][8oc] for ds_read_b128. 2 spatial outputs per thread.
__global__ void k_conv3(const float* __restrict__ in,
                        const float* __restrict__ w3,
                        const float* __restrict__ b3,
                        float* __restrict__ out) {
    __shared__ float wt[864][8];                     // 27,648 B
    int t = threadIdx.x;
    int ocg = blockIdx.x & 7;
    int b = blockIdx.x >> 3;                         // 256 blocks = 32 b x 8 ocg
    for (int i = t; i < 6912; i += 256) {
        int j = i & 7, ck = i >> 3;
        wt[ck][j] = w3[(ocg * 8 + j) * 864 + ck];
    }
    __syncthreads();

    int x = t & 7, y = (t >> 3) & 7, z0 = t >> 6;    // z0 in 0..3, also do z0+4
    const float* ib = in + b * 32 * 4096;
    float acc[2][8];
#pragma unroll
    for (int j = 0; j < 8; ++j) { acc[0][j] = b3[ocg * 8 + j]; acc[1][j] = b3[ocg * 8 + j]; }

    for (int c = 0; c < 32; ++c) {
        float ia[27], ib27[27];
#pragma unroll
        for (int kz = 0; kz < 3; ++kz)
#pragma unroll
            for (int ky = 0; ky < 3; ++ky)
#pragma unroll
                for (int kx = 0; kx < 3; ++kx) {
                    int iy = 2 * y + ky - 1, ix = 2 * x + kx - 1;
                    int iza = 2 * z0 + kz - 1, izb = 2 * (z0 + 4) + kz - 1;
                    bool oky = ((unsigned)iy < 16u) & ((unsigned)ix < 16u);
                    bool oka = oky & ((unsigned)iza < 16u);
                    bool okb = oky & ((unsigned)izb < 16u);
                    int k = kz * 9 + ky * 3 + kx;
                    ia[k]  = oka ? ib[c * 4096 + iza * 256 + iy * 16 + ix] : 0.0f;
                    ib27[k] = okb ? ib[c * 4096 + izb * 256 + iy * 16 + ix] : 0.0f;
                }
#pragma unroll
        for (int k = 0; k < 27; ++k) {
            float va = ia[k], vb = ib27[k];
            const float* wr = &wt[c * 27 + k][0];
#pragma unroll
            for (int j = 0; j < 8; ++j) {
                float w = wr[j];
                acc[0][j] = fmaf(w, va, acc[0][j]);
                acc[1][j] = fmaf(w, vb, acc[1][j]);
            }
        }
    }
    float* o = out + b * 32768 + y * 8 + x;
#pragma unroll
    for (int j = 0; j < 8; ++j) {
        o[(ocg * 8 + j) * 512 + z0 * 64]       = fmaxf(acc[0][j], 0.0f);
        o[(ocg * 8 + j) * 512 + (z0 + 4) * 64] = fmaxf(acc[1][j], 0.0f);
    }
}

// FC: out(32,128) = feat(32,32768) @ fc_w(128,32768)^T + fc_b.
// Grid = 128 f-chunks x 4 l-groups. fc_w read exactly once; feat staged in LDS.
// Partial sums accumulated with fp32 atomicAdd (out pre-zeroed).
__global__ void k_fc(const float* __restrict__ feat,
                     const float* __restrict__ fc_w,
                     const float* __restrict__ fc_b,
                     float* __restrict__ out) {
    __shared__ float lds[256 * 36];                  // [f][b], stride 36 (36,864 B)
    int fchunk = blockIdx.x & 127;
    int lg = blockIdx.x >> 7;                        // 0..3
    int t = threadIdx.x;
    int f0 = fchunk * 256;
    for (int b = 0; b < 32; ++b)
        lds[t * 36 + b] = feat[b * 32768 + f0 + t];  // coalesced load
    __syncthreads();

    int l = lg * 32 + (t >> 3);
    int bq = t & 7;                                  // 4 batches per thread
    const float* wrow = fc_w + l * 32768 + f0;
    float a0 = 0.f, a1 = 0.f, a2 = 0.f, a3 = 0.f;
    for (int f = 0; f < 256; ++f) {
        float wv = wrow[f];
        const float* p = &lds[f * 36 + bq * 4];
        a0 = fmaf(p[0], wv, a0);
        a1 = fmaf(p[1], wv, a1);
        a2 = fmaf(p[2], wv, a2);
        a3 = fmaf(p[3], wv, a3);
    }
    if (fchunk == 0) {
        float bb = fc_b[l];
        a0 += bb; a1 += bb; a2 += bb; a3 += bb;
    }
    int b0 = bq * 4;
    atomicAdd(&out[(b0 + 0) * 128 + l], a0);
    atomicAdd(&out[(b0 + 1) * 128 + l], a1);
    atomicAdd(&out[(b0 + 2) * 128 + l], a2);
    atomicAdd(&out[(b0 + 3) * 128 + l], a3);
}

extern "C" void kernel_launch(void* const* d_in, const int* in_sizes, int n_in,
                              void* d_out, int out_size, void* d_ws, size_t ws_size,
                              hipStream_t stream) {
    const float* coords = (const float*)d_in[0];
    const float* w1 = (const float*)d_in[1];
    const float* b1 = (const float*)d_in[2];
    const float* w2 = (const float*)d_in[3];
    const float* b2 = (const float*)d_in[4];
    const float* w3 = (const float*)d_in[5];
    const float* b3 = (const float*)d_in[6];
    const float* fc_w = (const float*)d_in[7];
    const float* fc_b = (const float*)d_in[8];

    unsigned char* grid_u8 = (unsigned char*)d_ws;
    float* c1 = (float*)((char*)d_ws + 8388608);
    float* c2 = (float*)((char*)d_ws + 75497472);
    float* feat = (float*)((char*)d_ws + 92274688);
    float* out = (float*)d_out;

    hipMemsetAsync(grid_u8, 0, 8388608, stream);
    hipMemsetAsync(out, 0, 32 * 128 * sizeof(float), stream);

    k_scatter<<<2048, 256, 0, stream>>>(coords, grid_u8);
    k_conv1<<<4096, 256, 0, stream>>>(grid_u8, w1, b1, c1);
    k_conv2<<<512, 256, 0, stream>>>(c1, w2, b2, c2);
    k_conv3<<<256, 256, 0, stream>>>(c2, w3, b3, feat);
    k_fc<<<512, 256, 0, stream>>>(feat, fc_w, fc_b, out);
}

// Round 5
// 374.178 us; speedup vs baseline: 1.3642x; 1.3642x over previous
//
#include <hip/hip_runtime.h>

// ---------------------------------------------------------------------------
// Naive3DConvEncoder: scatter -> conv1(1->16) -> conv2(16->32) -> conv3(32->64) -> FC
// All fp32. B=32, N=16384, G=64, LATENT=128.
// ws layout:
//   w2t     : offset 0 (aliases grid region, written AFTER conv1 is done)
//   w3t     : offset 65,536
//   grid_u8 : offset 0,          32*64^3 bytes            =  8,388,608
//   c1      : offset 8,388,608,  32*16*32^3 floats        = 67,108,864 B
//   c2      : offset 75,497,472, 32*32*16^3 floats        = 16,777,216 B
//   feat    : offset 92,274,688, 32*64*8^3 floats         =  4,194,304 B
// NOTE: w2t/w3t overlap grid_u8 (transpose launched after conv1, which is the
// last consumer of grid_u8). Stream ordering makes this safe; every launch
// redoes all steps -> safe under harness re-poisoning.
// ---------------------------------------------------------------------------

__global__ void k_scatter(const float* __restrict__ coords,
                          unsigned char* __restrict__ grid) {
    int i = blockIdx.x * 256 + threadIdx.x;          // 524288 threads
    float cx = coords[3 * i + 0];
    float cy = coords[3 * i + 1];
    float cz = coords[3 * i + 2];
    int ix = (int)((cx + 1.0f) * 0.5f * 63.0f);      // trunc like astype(int32)
    int iy = (int)((cy + 1.0f) * 0.5f * 63.0f);
    int iz = (int)((cz + 1.0f) * 0.5f * 63.0f);
    ix = min(max(ix, 0), 63);
    iy = min(max(iy, 0), 63);
    iz = min(max(iz, 0), 63);
    int b = i >> 14;                                 // N = 16384
    grid[((b * 64 + iz) * 64 + iy) * 64 + ix] = 1;
}

// conv1: binary grid (B,64^3) u8 -> (B,16,32^3) fp32, relu. 1M threads.
__global__ void k_conv1(const unsigned char* __restrict__ grid,
                        const float* __restrict__ w1,
                        const float* __restrict__ b1,
                        float* __restrict__ out) {
    int idx = blockIdx.x * 256 + threadIdx.x;
    int x = idx & 31, y = (idx >> 5) & 31, z = (idx >> 10) & 31, b = idx >> 15;
    const unsigned char* g = grid + b * 262144;
    float in27[27];
#pragma unroll
    for (int kz = 0; kz < 3; ++kz)
#pragma unroll
        for (int ky = 0; ky < 3; ++ky)
#pragma unroll
            for (int kx = 0; kx < 3; ++kx) {
                int iz = 2 * z + kz - 1, iy = 2 * y + ky - 1, ix = 2 * x + kx - 1;
                bool ok = ((unsigned)iz < 64u) & ((unsigned)iy < 64u) & ((unsigned)ix < 64u);
                in27[kz * 9 + ky * 3 + kx] = ok ? (float)g[(iz * 64 + iy) * 64 + ix] : 0.0f;
            }
    float* o = out + b * (16 * 32768) + (z * 1024 + y * 32 + x);
#pragma unroll
    for (int oc = 0; oc < 16; ++oc) {
        float acc = b1[oc];
#pragma unroll
        for (int k = 0; k < 27; ++k) acc = fmaf(w1[oc * 27 + k], in27[k], acc);
        o[oc * 32768] = fmaxf(acc, 0.0f);
    }
}

// Transpose weights to [ck][oc] so conv kernels read them wave-uniformly.
// w2 (32,16,27) -> w2t[(c*27+k)*32 + oc]; w3 (64,32,27) -> w3t[(c*27+k)*64 + oc]
__global__ void k_wtrans(const float* __restrict__ w2, float* __restrict__ w2t,
                         const float* __restrict__ w3, float* __restrict__ w3t) {
    int i = blockIdx.x * 256 + threadIdx.x;          // 270 blocks = 69120 threads
    if (i < 13824) {
        int oc = i / 432, rem = i - oc * 432;
        w2t[rem * 32 + oc] = w2[i];
    } else {
        int j = i - 13824;
        if (j < 55296) {
            int oc = j / 864, rem = j - oc * 864;
            w3t[rem * 64 + oc] = w3[j];
        }
    }
}

// conv2: (B,16,32^3) -> (B,32,16^3), relu.
// Block = (b, zo, ocg of 16 oc): 1024 blocks x 256 thr (x,y in 16x16).
// Input xy-plane slab (3 iz) staged in LDS, double-buffered, shifted +1 with
// zero border (no bounds checks in inner loop). Weights via wave-uniform
// s_load from w2t.
__global__ void k_conv2(const float* __restrict__ in,
                        const float* __restrict__ w2t,
                        const float* __restrict__ b2,
                        float* __restrict__ out) {
    __shared__ float ins[2][3][33][34];              // 26,928 B
    int blk = blockIdx.x;
    int ocg = blk & 1;
    int zo = (blk >> 1) & 15;
    int b = blk >> 5;
    int t = threadIdx.x;
    int x = t & 15, y = t >> 4;

    // zero everything once (borders stay zero; interior rewritten per c)
    float* lin = &ins[0][0][0][0];
    for (int i = t; i < 2 * 3 * 33 * 34; i += 256) lin[i] = 0.0f;

    const float* ib = in + b * (16 * 32768);

    // stage c=0 into buf 0: 3 planes x 1024 = 3072 elems, 12 per thread
#pragma unroll
    for (int r = 0; r < 12; ++r) {
        int idx = r * 256 + t;
        int kz = idx >> 10, pos = idx & 1023;
        int iz = 2 * zo + kz - 1;
        float v = ((unsigned)iz < 32u) ? ib[iz * 1024 + pos] : 0.0f;
        ins[0][kz][(pos >> 5) + 1][(pos & 31) + 1] = v;
    }
    __syncthreads();

    float acc[16];
#pragma unroll
    for (int j = 0; j < 16; ++j) acc[j] = b2[ocg * 16 + j];

    for (int c = 0; c < 16; ++c) {
        int cur = c & 1, nxt = cur ^ 1;
        // prefetch c+1 into registers (global latency hides under compute)
        float pfv[12];
        bool do_pf = (c + 1 < 16);
        if (do_pf) {
#pragma unroll
            for (int r = 0; r < 12; ++r) {
                int idx = r * 256 + t;
                int kz = idx >> 10, pos = idx & 1023;
                int iz = 2 * zo + kz - 1;
                pfv[r] = ((unsigned)iz < 32u) ? ib[(c + 1) * 32768 + iz * 1024 + pos] : 0.0f;
            }
        }
        // compute from ins[cur]
        const float* wt = w2t + c * 27 * 32 + ocg * 16;
#pragma unroll
        for (int kz = 0; kz < 3; ++kz)
#pragma unroll
            for (int ky = 0; ky < 3; ++ky)
#pragma unroll
                for (int kx = 0; kx < 3; ++kx) {
                    float v = ins[cur][kz][2 * y + ky][2 * x + kx];
                    const float* w = wt + (kz * 9 + ky * 3 + kx) * 32;
#pragma unroll
                    for (int j = 0; j < 16; ++j)
                        acc[j] = fmaf(w[j], v, acc[j]);
                }
        if (do_pf) {
#pragma unroll
            for (int r = 0; r < 12; ++r) {
                int idx = r * 256 + t;
                int kz = idx >> 10, pos = idx & 1023;
                ins[nxt][kz][(pos >> 5) + 1][(pos & 31) + 1] = pfv[r];
            }
        }
        __syncthreads();
    }

    float* o = out + b * (32 * 4096) + zo * 256 + y * 16 + x;
#pragma unroll
    for (int j = 0; j < 16; ++j)
        o[(ocg * 16 + j) * 4096] = fmaxf(acc[j], 0.0f);
}

// conv3: (B,32,16^3) -> (B,64,8^3), relu, writes feat directly.
// Block = (b, zo, ocg of 32 oc): 512 blocks x 256 thr.
// Thread = (sp 0..63 = 8y x 8x, ocO 0..3 -> 8 oc each). Wave-uniform weights.
__global__ void k_conv3(const float* __restrict__ in,
                        const float* __restrict__ w3t,
                        const float* __restrict__ b3,
                        float* __restrict__ out) {
    __shared__ float ins[2][3][17][18];              // 7,344 B
    int blk = blockIdx.x;
    int ocg = blk & 1;                               // 32 oc per block
    int zo = (blk >> 1) & 7;
    int b = blk >> 4;
    int t = threadIdx.x;
    int sp = t & 63;
    int x = sp & 7, y = sp >> 3;
    int ocO = t >> 6;                                // wave index -> 8 oc
    int oc0 = ocg * 32 + ocO * 8;

    float* lin = &ins[0][0][0][0];
    for (int i = t; i < 2 * 3 * 17 * 18; i += 256) lin[i] = 0.0f;

    const float* ib = in + b * (32 * 4096);

    // stage c=0: 3 planes x 256 = 768 elems, 3 per thread
#pragma unroll
    for (int r = 0; r < 3; ++r) {
        int idx = r * 256 + t;                       // 0..767
        int kz = idx >> 8, pos = idx & 255;
        int iz = 2 * zo + kz - 1;
        float v = ((unsigned)iz < 16u) ? ib[iz * 256 + pos] : 0.0f;
        ins[0][kz][(pos >> 4) + 1][(pos & 15) + 1] = v;
    }
    __syncthreads();

    float acc[8];
#pragma unroll
    for (int j = 0; j < 8; ++j) acc[j] = b3[oc0 + j];

    for (int c = 0; c < 32; ++c) {
        int cur = c & 1, nxt = cur ^ 1;
        float pfv[3];
        bool do_pf = (c + 1 < 32);
        if (do_pf) {
#pragma unroll
            for (int r = 0; r < 3; ++r) {
                int idx = r * 256 + t;
                int kz = idx >> 8, pos = idx & 255;
                int iz = 2 * zo + kz - 1;
                pfv[r] = ((unsigned)iz < 16u) ? ib[(c + 1) * 4096 + iz * 256 + pos] : 0.0f;
            }
        }
        const float* wt = w3t + c * 27 * 64 + oc0;
#pragma unroll
        for (int kz = 0; kz < 3; ++kz)
#pragma unroll
            for (int ky = 0; ky < 3; ++ky)
#pragma unroll
                for (int kx = 0; kx < 3; ++kx) {
                    float v = ins[cur][kz][2 * y + ky][2 * x + kx];
                    const float* w = wt + (kz * 9 + ky * 3 + kx) * 64;
#pragma unroll
                    for (int j = 0; j < 8; ++j)
                        acc[j] = fmaf(w[j], v, acc[j]);
                }
        if (do_pf) {
#pragma unroll
            for (int r = 0; r < 3; ++r) {
                int idx = r * 256 + t;
                int kz = idx >> 8, pos = idx & 255;
                ins[nxt][kz][(pos >> 4) + 1][(pos & 15) + 1] = pfv[r];
            }
        }
        __syncthreads();
    }

    float* o = out + b * 32768 + zo * 64 + y * 8 + x;
#pragma unroll
    for (int j = 0; j < 8; ++j)
        o[(oc0 + j) * 512] = fmaxf(acc[j], 0.0f);
}

// FC: out(32,128) = feat(32,32768) @ fc_w(128,32768)^T + fc_b.
__global__ void k_fc(const float* __restrict__ feat,
                     const float* __restrict__ fc_w,
                     const float* __restrict__ fc_b,
                     float* __restrict__ out) {
    __shared__ float lds[256 * 36];                  // 36,864 B
    int fchunk = blockIdx.x & 127;
    int lg = blockIdx.x >> 7;
    int t = threadIdx.x;
    int f0 = fchunk * 256;
    for (int b = 0; b < 32; ++b)
        lds[t * 36 + b] = feat[b * 32768 + f0 + t];
    __syncthreads();

    int l = lg * 32 + (t >> 3);
    int bq = t & 7;
    const float* wrow = fc_w + l * 32768 + f0;
    float a0 = 0.f, a1 = 0.f, a2 = 0.f, a3 = 0.f;
    for (int f = 0; f < 256; ++f) {
        float wv = wrow[f];
        const float* p = &lds[f * 36 + bq * 4];
        a0 = fmaf(p[0], wv, a0);
        a1 = fmaf(p[1], wv, a1);
        a2 = fmaf(p[2], wv, a2);
        a3 = fmaf(p[3], wv, a3);
    }
    if (fchunk == 0) {
        float bb = fc_b[l];
        a0 += bb; a1 += bb; a2 += bb; a3 += bb;
    }
    int b0 = bq * 4;
    atomicAdd(&out[(b0 + 0) * 128 + l], a0);
    atomicAdd(&out[(b0 + 1) * 128 + l], a1);
    atomicAdd(&out[(b0 + 2) * 128 + l], a2);
    atomicAdd(&out[(b0 + 3) * 128 + l], a3);
}

extern "C" void kernel_launch(void* const* d_in, const int* in_sizes, int n_in,
                              void* d_out, int out_size, void* d_ws, size_t ws_size,
                              hipStream_t stream) {
    const float* coords = (const float*)d_in[0];
    const float* w1 = (const float*)d_in[1];
    const float* b1 = (const float*)d_in[2];
    const float* w2 = (const float*)d_in[3];
    const float* b2 = (const float*)d_in[4];
    const float* w3 = (const float*)d_in[5];
    const float* b3 = (const float*)d_in[6];
    const float* fc_w = (const float*)d_in[7];
    const float* fc_b = (const float*)d_in[8];

    unsigned char* grid_u8 = (unsigned char*)d_ws;
    float* w2t = (float*)d_ws;                       // aliases grid (used after conv1)
    float* w3t = (float*)((char*)d_ws + 65536);
    float* c1 = (float*)((char*)d_ws + 8388608);
    float* c2 = (float*)((char*)d_ws + 75497472);
    float* feat = (float*)((char*)d_ws + 92274688);
    float* out = (float*)d_out;

    hipMemsetAsync(grid_u8, 0, 8388608, stream);
    hipMemsetAsync(out, 0, 32 * 128 * sizeof(float), stream);

    k_scatter<<<2048, 256, 0, stream>>>(coords, grid_u8);
    k_conv1<<<4096, 256, 0, stream>>>(grid_u8, w1, b1, c1);
    k_wtrans<<<270, 256, 0, stream>>>(w2, w2t, w3, w3t);   // grid_u8 dead now
    k_conv2<<<1024, 256, 0, stream>>>(c1, w2t, b2, c2);
    k_conv3<<<512, 256, 0, stream>>>(c2, w3t, b3, feat);
    k_fc<<<512, 256, 0, stream>>>(feat, fc_w, fc_b, out);
}

// Round 6
// 256.578 us; speedup vs baseline: 1.9895x; 1.4583x over previous
//
#include <hip/hip_runtime.h>
#include <hip/hip_bf16.h>

// ---------------------------------------------------------------------------
// Naive3DConvEncoder: scatter -> conv1(1->16) -> conv2(16->32, bf16 MFMA)
//                      -> conv3(32->64) -> FC.  B=32, N=16384, G=64.
// ws layout:
//   grid_u8 : 0          (8,388,608 B)   [dead after conv1]
//   w2b     : 65,536     (28,672 B bf16 [28 shifts][32 oc][16 c], aliases grid)
//   w3t     : 131,072    (221,184 B fp32, aliases grid)
//   c1b     : 8,388,608  (33,554,432 B bf16 channels-last [b][z][y][x][c16])
//   c2      : 75,497,472 (16,777,216 B fp32 [b][oc][z][y][x])
//   feat    : 92,274,688 (4,194,304 B fp32)
// ---------------------------------------------------------------------------

typedef __attribute__((ext_vector_type(8))) short bf16x8;
typedef __attribute__((ext_vector_type(4))) float f32x4;

__device__ inline unsigned short f2bf(float f) {
    __hip_bfloat16 h = __float2bfloat16(f);
    return *reinterpret_cast<unsigned short*>(&h);
}

__global__ void k_scatter(const float* __restrict__ coords,
                          unsigned char* __restrict__ grid) {
    int i = blockIdx.x * 256 + threadIdx.x;          // 524288 threads
    float cx = coords[3 * i + 0];
    float cy = coords[3 * i + 1];
    float cz = coords[3 * i + 2];
    int ix = (int)((cx + 1.0f) * 0.5f * 63.0f);      // trunc like astype(int32)
    int iy = (int)((cy + 1.0f) * 0.5f * 63.0f);
    int iz = (int)((cz + 1.0f) * 0.5f * 63.0f);
    ix = min(max(ix, 0), 63);
    iy = min(max(iy, 0), 63);
    iz = min(max(iz, 0), 63);
    int b = i >> 14;
    grid[((b * 64 + iz) * 64 + iy) * 64 + ix] = 1;
}

// conv1: binary grid (B,64^3) u8 -> c1b channels-last bf16 [b][z][y][x][c16].
__global__ void k_conv1(const unsigned char* __restrict__ grid,
                        const float* __restrict__ w1,
                        const float* __restrict__ b1,
                        unsigned short* __restrict__ c1b) {
    int idx = blockIdx.x * 256 + threadIdx.x;        // 1,048,576 threads
    int x = idx & 31, y = (idx >> 5) & 31, z = (idx >> 10) & 31, b = idx >> 15;
    const unsigned char* g = grid + b * 262144;
    float in27[27];
#pragma unroll
    for (int kz = 0; kz < 3; ++kz)
#pragma unroll
        for (int ky = 0; ky < 3; ++ky)
#pragma unroll
            for (int kx = 0; kx < 3; ++kx) {
                int iz = 2 * z + kz - 1, iy = 2 * y + ky - 1, ix = 2 * x + kx - 1;
                bool ok = ((unsigned)iz < 64u) & ((unsigned)iy < 64u) & ((unsigned)ix < 64u);
                in27[kz * 9 + ky * 3 + kx] = ok ? (float)g[(iz * 64 + iy) * 64 + ix] : 0.0f;
            }
    float r[16];
#pragma unroll
    for (int oc = 0; oc < 16; ++oc) {
        float acc = b1[oc];
#pragma unroll
        for (int k = 0; k < 27; ++k) acc = fmaf(w1[oc * 27 + k], in27[k], acc);
        r[oc] = fmaxf(acc, 0.0f);
    }
    unsigned int dw[8];
#pragma unroll
    for (int j = 0; j < 8; ++j)
        dw[j] = (unsigned int)f2bf(r[2 * j]) | ((unsigned int)f2bf(r[2 * j + 1]) << 16);
    char* base = (char*)c1b + (size_t)idx * 32;
    *(int4*)base        = int4{(int)dw[0], (int)dw[1], (int)dw[2], (int)dw[3]};
    *(int4*)(base + 16) = int4{(int)dw[4], (int)dw[5], (int)dw[6], (int)dw[7]};
}

// Weight prep: w2b bf16 [sh 28][oc 32][c 16] (sh 27 zero-padded); w3t fp32 [ck][oc].
__global__ void k_wtrans(const float* __restrict__ w2, unsigned short* __restrict__ w2b,
                         const float* __restrict__ w3, float* __restrict__ w3t) {
    int i = blockIdx.x * 256 + threadIdx.x;          // 272 blocks = 69632 threads
    if (i < 14336) {
        int sh = i >> 9, oc = (i >> 4) & 31, c = i & 15;
        float v = (sh < 27) ? w2[oc * 432 + c * 27 + sh] : 0.0f;
        w2b[i] = f2bf(v);
    } else {
        int j = i - 14336;
        if (j < 55296) {
            int oc = j / 864, rem = j - oc * 864;
            w3t[rem * 64 + oc] = w3[j];
        }
    }
}

// ---------------------------------------------------------------------------
// conv2 as implicit GEMM on MFMA 16x16x32 bf16.
// GEMM: M=256 spatial (x-major tiles of 16 y), N=32 oc, K=432 (27 shifts x 16c,
// walked as 14 shift-pairs of K=32). Block=(b,zo): stages the whole 3-plane
// input halo slab in LDS ONCE, parity-split rows (even/odd iy) with 1072 B
// (odd x 16B) row stride -> conflict-free ds_read_b128 A-fragments despite
// the stride-2 conv. No barriers inside the K-loop.
// LDS per iz-plane: even rows 17*1072=18224 B, odd 16*1072=17152 B (35376 B);
// 3 planes = 106128 B.
// ---------------------------------------------------------------------------
__device__ constexpr int abase(int sh) {
    return (sh / 9) * 35376 + (((sh % 9) / 3) & 1) * 18224 +
           (((sh % 9) / 3) >> 1) * 1072 + (sh % 3) * 32;
}

__global__ __launch_bounds__(512) void k_conv2_mfma(
        const unsigned short* __restrict__ c1b,
        const unsigned short* __restrict__ w2b,
        const float* __restrict__ b2,
        float* __restrict__ out) {
    __shared__ __align__(16) char smem[106128];
    const int t = threadIdx.x;
    const int b = blockIdx.x >> 4;
    const int zo = blockIdx.x & 15;
    const int lane = t & 63;
    const int wid = t >> 6;                          // 8 waves

    // zero borders (disjoint from staged interior -> no extra barrier)
    {
        const int4 z4 = {0, 0, 0, 0};
        if (t < 198) {                               // even row 0 (iy_in = -1)
            int p = t / 66, r = t % 66;
            int col = r >> 1, h = r & 1;
            *(int4*)(smem + p * 35376 + col * 32 + h * 16) = z4;
        }
        if (t >= 256 && t < 454) {                   // col 0 (ix_in = -1), all rows
            int i = t - 256;
            int p = i / 66, r = i % 66;
            int row33 = r >> 1, h = r & 1;           // 0..16 even, 17..32 odd
            int off = (row33 < 17) ? row33 * 1072 : 18224 + (row33 - 17) * 1072;
            *(int4*)(smem + p * 35376 + off + h * 16) = z4;
        }
    }

    // stage 3 iz-planes of c1b (32x32 slots of 32 B each)
    const char* src = (const char*)c1b + (size_t)b * (32768 * 32);
#pragma unroll
    for (int i = 0; i < 6; ++i) {
        const int p = i >> 1;                        // plane = kz
        int pos = ((i & 1) << 9) + t;                // 0..1023
        int iy = pos >> 5, ix = pos & 31;
        int iz = 2 * zo + p - 1;                     // -1..31 (only -1 possible OOB)
        int4 v0 = {0, 0, 0, 0}, v1 = {0, 0, 0, 0};
        if (iz >= 0) {
            const char* gp = src + ((size_t)(iz * 1024 + pos)) * 32;
            v0 = *(const int4*)gp;
            v1 = *(const int4*)(gp + 16);
        }
        int iy_st = iy + 1;
        char* d = smem + p * 35376 + ((iy_st & 1) ? 18224 : 0) + (iy_st >> 1) * 1072 +
                  (ix + 1) * 32;
        *(int4*)d = v0;
        *(int4*)(d + 16) = v1;
    }
    __syncthreads();

    // MFMA main loop: wave wid owns x in {2*wid, 2*wid+1}, both oc-tiles.
    const int y = lane & 15;
    const int g = lane >> 4;
    const int h = g & 1;
    const int s = g >> 1;
    const int laneA = y * 1072 + h * 16;
    const int laneB = (lane & 15) * 32 + h * 16 + s * 1024;
    const int x0 = wid * 2;
    const char* wbase = (const char*)w2b;

    f32x4 acc00 = {0, 0, 0, 0}, acc01 = {0, 0, 0, 0};
    f32x4 acc10 = {0, 0, 0, 0}, acc11 = {0, 0, 0, 0};

#pragma unroll
    for (int sp = 0; sp < 14; ++sp) {
        const int sh0 = 2 * sp;
        const int sh1 = (2 * sp + 1 < 27) ? 2 * sp + 1 : 26;  // A-pad: reuse 26 (B=0)
        const int a0 = abase(sh0);
        const int d01 = abase(sh1) - a0;
        const int addrA = laneA + a0 + (s ? d01 : 0) + x0 * 64;
        bf16x8 A0 = *(const bf16x8*)(smem + addrA);
        bf16x8 A1 = *(const bf16x8*)(smem + addrA + 64);
        const char* wb = wbase + sp * 2048 + laneB;  // sh stride 1024 B, s in laneB
        bf16x8 B0 = *(const bf16x8*)wb;
        bf16x8 B1 = *(const bf16x8*)(wb + 512);      // oc-tile 1
        acc00 = __builtin_amdgcn_mfma_f32_16x16x32_bf16(A0, B0, acc00, 0, 0, 0);
        acc01 = __builtin_amdgcn_mfma_f32_16x16x32_bf16(A0, B1, acc01, 0, 0, 0);
        acc10 = __builtin_amdgcn_mfma_f32_16x16x32_bf16(A1, B0, acc10, 0, 0, 0);
        acc11 = __builtin_amdgcn_mfma_f32_16x16x32_bf16(A1, B1, acc11, 0, 0, 0);
    }

    // epilogue: transpose through LDS (slab dead), coalesced fp32 store.
    __syncthreads();
    float* sOut = (float*)smem;                      // [32 oc][257] (pad vs bank 0)
    {
        int ocl = lane & 15;
        int yb = (lane >> 4) * 4;                    // D row = (lane>>4)*4 + r
#pragma unroll
        for (int r = 0; r < 4; ++r) {
            sOut[ocl * 257        + (yb + r) * 16 + x0    ] = acc00[r];
            sOut[(ocl + 16) * 257 + (yb + r) * 16 + x0    ] = acc01[r];
            sOut[ocl * 257        + (yb + r) * 16 + x0 + 1] = acc10[r];
            sOut[(ocl + 16) * 257 + (yb + r) * 16 + x0 + 1] = acc11[r];
        }
    }
    __syncthreads();
    float* dst = out + (size_t)b * 131072 + zo * 256;
    int m = t & 255;
    int oc_half = t >> 8;
#pragma unroll
    for (int i = 0; i < 16; ++i) {
        int oc = i * 2 + oc_half;
        float v = sOut[oc * 257 + m] + b2[oc];
        dst[oc * 4096 + m] = fmaxf(v, 0.0f);
    }
}

// conv3: (B,32,16^3) -> (B,64,8^3), relu, fp32 (unchanged from passing round).
__global__ void k_conv3(const float* __restrict__ in,
                        const float* __restrict__ w3t,
                        const float* __restrict__ b3,
                        float* __restrict__ out) {
    __shared__ float ins[2][3][17][18];
    int blk = blockIdx.x;
    int ocg = blk & 1;
    int zo = (blk >> 1) & 7;
    int b = blk >> 4;
    int t = threadIdx.x;
    int sp = t & 63;
    int x = sp & 7, y = sp >> 3;
    int ocO = t >> 6;
    int oc0 = ocg * 32 + ocO * 8;

    float* lin = &ins[0][0][0][0];
    for (int i = t; i < 2 * 3 * 17 * 18; i += 256) lin[i] = 0.0f;

    const float* ib = in + b * (32 * 4096);
#pragma unroll
    for (int r = 0; r < 3; ++r) {
        int idx = r * 256 + t;
        int kz = idx >> 8, pos = idx & 255;
        int iz = 2 * zo + kz - 1;
        float v = ((unsigned)iz < 16u) ? ib[iz * 256 + pos] : 0.0f;
        ins[0][kz][(pos >> 4) + 1][(pos & 15) + 1] = v;
    }
    __syncthreads();

    float acc[8];
#pragma unroll
    for (int j = 0; j < 8; ++j) acc[j] = b3[oc0 + j];

    for (int c = 0; c < 32; ++c) {
        int cur = c & 1, nxt = cur ^ 1;
        float pfv[3];
        bool do_pf = (c + 1 < 32);
        if (do_pf) {
#pragma unroll
            for (int r = 0; r < 3; ++r) {
                int idx = r * 256 + t;
                int kz = idx >> 8, pos = idx & 255;
                int iz = 2 * zo + kz - 1;
                pfv[r] = ((unsigned)iz < 16u) ? ib[(c + 1) * 4096 + iz * 256 + pos] : 0.0f;
            }
        }
        const float* wt = w3t + c * 27 * 64 + oc0;
#pragma unroll
        for (int kz = 0; kz < 3; ++kz)
#pragma unroll
            for (int ky = 0; ky < 3; ++ky)
#pragma unroll
                for (int kx = 0; kx < 3; ++kx) {
                    float v = ins[cur][kz][2 * y + ky][2 * x + kx];
                    const float* w = wt + (kz * 9 + ky * 3 + kx) * 64;
#pragma unroll
                    for (int j = 0; j < 8; ++j)
                        acc[j] = fmaf(w[j], v, acc[j]);
                }
        if (do_pf) {
#pragma unroll
            for (int r = 0; r < 3; ++r) {
                int idx = r * 256 + t;
                int kz = idx >> 8, pos = idx & 255;
                ins[nxt][kz][(pos >> 4) + 1][(pos & 15) + 1] = pfv[r];
            }
        }
        __syncthreads();
    }

    float* o = out + b * 32768 + zo * 64 + y * 8 + x;
#pragma unroll
    for (int j = 0; j < 8; ++j)
        o[(oc0 + j) * 512] = fmaxf(acc[j], 0.0f);
}

// FC: out(32,128) = feat(32,32768) @ fc_w(128,32768)^T + fc_b. (unchanged)
__global__ void k_fc(const float* __restrict__ feat,
                     const float* __restrict__ fc_w,
                     const float* __restrict__ fc_b,
                     float* __restrict__ out) {
    __shared__ float lds[256 * 36];
    int fchunk = blockIdx.x & 127;
    int lg = blockIdx.x >> 7;
    int t = threadIdx.x;
    int f0 = fchunk * 256;
    for (int b = 0; b < 32; ++b)
        lds[t * 36 + b] = feat[b * 32768 + f0 + t];
    __syncthreads();

    int l = lg * 32 + (t >> 3);
    int bq = t & 7;
    const float* wrow = fc_w + l * 32768 + f0;
    float a0 = 0.f, a1 = 0.f, a2 = 0.f, a3 = 0.f;
    for (int f = 0; f < 256; ++f) {
        float wv = wrow[f];
        const float* p = &lds[f * 36 + bq * 4];
        a0 = fmaf(p[0], wv, a0);
        a1 = fmaf(p[1], wv, a1);
        a2 = fmaf(p[2], wv, a2);
        a3 = fmaf(p[3], wv, a3);
    }
    if (fchunk == 0) {
        float bb = fc_b[l];
        a0 += bb; a1 += bb; a2 += bb; a3 += bb;
    }
    int b0 = bq * 4;
    atomicAdd(&out[(b0 + 0) * 128 + l], a0);
    atomicAdd(&out[(b0 + 1) * 128 + l], a1);
    atomicAdd(&out[(b0 + 2) * 128 + l], a2);
    atomicAdd(&out[(b0 + 3) * 128 + l], a3);
}

extern "C" void kernel_launch(void* const* d_in, const int* in_sizes, int n_in,
                              void* d_out, int out_size, void* d_ws, size_t ws_size,
                              hipStream_t stream) {
    const float* coords = (const float*)d_in[0];
    const float* w1 = (const float*)d_in[1];
    const float* b1 = (const float*)d_in[2];
    const float* w2 = (const float*)d_in[3];
    const float* b2 = (const float*)d_in[4];
    const float* w3 = (const float*)d_in[5];
    const float* b3 = (const float*)d_in[6];
    const float* fc_w = (const float*)d_in[7];
    const float* fc_b = (const float*)d_in[8];

    unsigned char* grid_u8 = (unsigned char*)d_ws;
    unsigned short* w2b = (unsigned short*)((char*)d_ws + 65536);   // aliases grid
    float* w3t = (float*)((char*)d_ws + 131072);                    // aliases grid
    unsigned short* c1b = (unsigned short*)((char*)d_ws + 8388608);
    float* c2 = (float*)((char*)d_ws + 75497472);
    float* feat = (float*)((char*)d_ws + 92274688);
    float* out = (float*)d_out;

    hipMemsetAsync(grid_u8, 0, 8388608, stream);
    hipMemsetAsync(out, 0, 32 * 128 * sizeof(float), stream);

    k_scatter<<<2048, 256, 0, stream>>>(coords, grid_u8);
    k_conv1<<<4096, 256, 0, stream>>>(grid_u8, w1, b1, c1b);
    k_wtrans<<<272, 256, 0, stream>>>(w2, w2b, w3, w3t);            // grid dead now
    k_conv2_mfma<<<512, 512, 0, stream>>>(c1b, w2b, b2, c2);
    k_conv3<<<512, 256, 0, stream>>>(c2, w3t, b3, feat);
    k_fc<<<512, 256, 0, stream>>>(feat, fc_w, fc_b, out);
}

// Round 7
// 165.857 us; speedup vs baseline: 3.0778x; 1.5470x over previous
//
#include <hip/hip_runtime.h>
#include <hip/hip_bf16.h>

// ---------------------------------------------------------------------------
// Naive3DConvEncoder: scatter -> conv1(1->16) -> conv2(16->32, bf16 MFMA)
//                      -> conv3(32->64, bf16 MFMA) -> FC.  B=32, N=16384, G=64.
// ws layout:
//   grid_u8 : 0          (8,388,608 B)   [dead after conv1]
//   w2b     : 65,536     (28,672 B bf16 [28 sh][32 oc][16 c], aliases grid)
//   w3b     : 131,072    (110,592 B bf16 [27 sh][64 oc][32 c], aliases grid)
//   c1b     : 8,388,608  (33,554,432 B bf16 channels-last [b][z][y][x][c16])
//   c2b     : 75,497,472 (8,388,608 B bf16 channels-last [b][z][y][x][c32])
//   feat    : 92,274,688 (4,194,304 B fp32 [b][oc][z][y][x])
// ---------------------------------------------------------------------------

typedef __attribute__((ext_vector_type(8))) short bf16x8;
typedef __attribute__((ext_vector_type(4))) float f32x4;

__device__ inline unsigned short f2bf(float f) {
    __hip_bfloat16 h = __float2bfloat16(f);
    return *reinterpret_cast<unsigned short*>(&h);
}

__global__ void k_scatter(const float* __restrict__ coords,
                          unsigned char* __restrict__ grid) {
    int i = blockIdx.x * 256 + threadIdx.x;          // 524288 threads
    float cx = coords[3 * i + 0];
    float cy = coords[3 * i + 1];
    float cz = coords[3 * i + 2];
    int ix = (int)((cx + 1.0f) * 0.5f * 63.0f);      // trunc like astype(int32)
    int iy = (int)((cy + 1.0f) * 0.5f * 63.0f);
    int iz = (int)((cz + 1.0f) * 0.5f * 63.0f);
    ix = min(max(ix, 0), 63);
    iy = min(max(iy, 0), 63);
    iz = min(max(iz, 0), 63);
    int b = i >> 14;
    grid[((b * 64 + iz) * 64 + iy) * 64 + ix] = 1;
}

// conv1: binary grid (B,64^3) u8 -> c1b channels-last bf16 [b][z][y][x][c16].
__global__ void k_conv1(const unsigned char* __restrict__ grid,
                        const float* __restrict__ w1,
                        const float* __restrict__ b1,
                        unsigned short* __restrict__ c1b) {
    int idx = blockIdx.x * 256 + threadIdx.x;        // 1,048,576 threads
    int x = idx & 31, y = (idx >> 5) & 31, z = (idx >> 10) & 31, b = idx >> 15;
    const unsigned char* g = grid + b * 262144;
    float in27[27];
#pragma unroll
    for (int kz = 0; kz < 3; ++kz)
#pragma unroll
        for (int ky = 0; ky < 3; ++ky)
#pragma unroll
            for (int kx = 0; kx < 3; ++kx) {
                int iz = 2 * z + kz - 1, iy = 2 * y + ky - 1, ix = 2 * x + kx - 1;
                bool ok = ((unsigned)iz < 64u) & ((unsigned)iy < 64u) & ((unsigned)ix < 64u);
                in27[kz * 9 + ky * 3 + kx] = ok ? (float)g[(iz * 64 + iy) * 64 + ix] : 0.0f;
            }
    float r[16];
#pragma unroll
    for (int oc = 0; oc < 16; ++oc) {
        float acc = b1[oc];
#pragma unroll
        for (int k = 0; k < 27; ++k) acc = fmaf(w1[oc * 27 + k], in27[k], acc);
        r[oc] = fmaxf(acc, 0.0f);
    }
    unsigned int dw[8];
#pragma unroll
    for (int j = 0; j < 8; ++j)
        dw[j] = (unsigned int)f2bf(r[2 * j]) | ((unsigned int)f2bf(r[2 * j + 1]) << 16);
    char* base = (char*)c1b + (size_t)idx * 32;
    *(int4*)base        = int4{(int)dw[0], (int)dw[1], (int)dw[2], (int)dw[3]};
    *(int4*)(base + 16) = int4{(int)dw[4], (int)dw[5], (int)dw[6], (int)dw[7]};
}

// Weight prep: w2b bf16 [sh 28][oc 32][c 16] (sh 27 zero-padded);
//              w3b bf16 [sh 27][oc 64][c 32].
__global__ void k_wtrans(const float* __restrict__ w2, unsigned short* __restrict__ w2b,
                         const float* __restrict__ w3, unsigned short* __restrict__ w3b) {
    int i = blockIdx.x * 256 + threadIdx.x;          // 272 blocks = 69632 threads
    if (i < 14336) {
        int sh = i >> 9, oc = (i >> 4) & 31, c = i & 15;
        float v = (sh < 27) ? w2[oc * 432 + c * 27 + sh] : 0.0f;
        w2b[i] = f2bf(v);
    } else {
        int j = i - 14336;
        if (j < 55296) {
            int sh = j >> 11, oc = (j >> 5) & 63, c = j & 31;
            w3b[j] = f2bf(w3[oc * 864 + c * 27 + sh]);
        }
    }
}

// ---------------------------------------------------------------------------
// conv2 as implicit GEMM on MFMA 16x16x32 bf16 (parity-split-y slab, as r6).
// Epilogue now emits channels-last bf16 c2b.
// ---------------------------------------------------------------------------
__device__ constexpr int abase(int sh) {
    return (sh / 9) * 35376 + (((sh % 9) / 3) & 1) * 18224 +
           (((sh % 9) / 3) >> 1) * 1072 + (sh % 3) * 32;
}

__global__ __launch_bounds__(512) void k_conv2_mfma(
        const unsigned short* __restrict__ c1b,
        const unsigned short* __restrict__ w2b,
        const float* __restrict__ b2,
        unsigned short* __restrict__ c2b) {
    __shared__ __align__(16) char smem[106128];
    const int t = threadIdx.x;
    const int b = blockIdx.x >> 4;
    const int zo = blockIdx.x & 15;
    const int lane = t & 63;
    const int wid = t >> 6;                          // 8 waves

    // zero borders (disjoint from staged interior -> no extra barrier)
    {
        const int4 z4 = {0, 0, 0, 0};
        if (t < 198) {                               // even row 0 (iy_in = -1)
            int p = t / 66, r = t % 66;
            int col = r >> 1, h = r & 1;
            *(int4*)(smem + p * 35376 + col * 32 + h * 16) = z4;
        }
        if (t >= 256 && t < 454) {                   // col 0 (ix_in = -1), all rows
            int i = t - 256;
            int p = i / 66, r = i % 66;
            int row33 = r >> 1, h = r & 1;
            int off = (row33 < 17) ? row33 * 1072 : 18224 + (row33 - 17) * 1072;
            *(int4*)(smem + p * 35376 + off + h * 16) = z4;
        }
    }

    // stage 3 iz-planes of c1b (32x32 slots of 32 B each)
    const char* src = (const char*)c1b + (size_t)b * (32768 * 32);
#pragma unroll
    for (int i = 0; i < 6; ++i) {
        const int p = i >> 1;
        int pos = ((i & 1) << 9) + t;                // 0..1023
        int iy = pos >> 5, ix = pos & 31;
        int iz = 2 * zo + p - 1;
        int4 v0 = {0, 0, 0, 0}, v1 = {0, 0, 0, 0};
        if (iz >= 0) {
            const char* gp = src + ((size_t)(iz * 1024 + pos)) * 32;
            v0 = *(const int4*)gp;
            v1 = *(const int4*)(gp + 16);
        }
        int iy_st = iy + 1;
        char* d = smem + p * 35376 + ((iy_st & 1) ? 18224 : 0) + (iy_st >> 1) * 1072 +
                  (ix + 1) * 32;
        *(int4*)d = v0;
        *(int4*)(d + 16) = v1;
    }
    __syncthreads();

    const int y = lane & 15;
    const int g = lane >> 4;
    const int h = g & 1;
    const int s = g >> 1;
    const int laneA = y * 1072 + h * 16;
    const int laneB = (lane & 15) * 32 + h * 16 + s * 1024;
    const int x0 = wid * 2;
    const char* wbase = (const char*)w2b;

    f32x4 acc00 = {0, 0, 0, 0}, acc01 = {0, 0, 0, 0};
    f32x4 acc10 = {0, 0, 0, 0}, acc11 = {0, 0, 0, 0};

#pragma unroll
    for (int sp = 0; sp < 14; ++sp) {
        const int sh0 = 2 * sp;
        const int sh1 = (2 * sp + 1 < 27) ? 2 * sp + 1 : 26;
        const int a0 = abase(sh0);
        const int d01 = abase(sh1) - a0;
        const int addrA = laneA + a0 + (s ? d01 : 0) + x0 * 64;
        bf16x8 A0 = *(const bf16x8*)(smem + addrA);
        bf16x8 A1 = *(const bf16x8*)(smem + addrA + 64);
        const char* wb = wbase + sp * 2048 + laneB;
        bf16x8 B0 = *(const bf16x8*)wb;
        bf16x8 B1 = *(const bf16x8*)(wb + 512);
        acc00 = __builtin_amdgcn_mfma_f32_16x16x32_bf16(A0, B0, acc00, 0, 0, 0);
        acc01 = __builtin_amdgcn_mfma_f32_16x16x32_bf16(A0, B1, acc01, 0, 0, 0);
        acc10 = __builtin_amdgcn_mfma_f32_16x16x32_bf16(A1, B0, acc10, 0, 0, 0);
        acc11 = __builtin_amdgcn_mfma_f32_16x16x32_bf16(A1, B1, acc11, 0, 0, 0);
    }

    // epilogue: transpose through LDS; pack bf16 channels-last c2b.
    __syncthreads();
    float* sOut = (float*)smem;                      // [32 oc][257]
    {
        int ocl = lane & 15;
        int yb = (lane >> 4) * 4;
#pragma unroll
        for (int r = 0; r < 4; ++r) {
            sOut[ocl * 257        + (yb + r) * 16 + x0    ] = acc00[r];
            sOut[(ocl + 16) * 257 + (yb + r) * 16 + x0    ] = acc01[r];
            sOut[ocl * 257        + (yb + r) * 16 + x0 + 1] = acc10[r];
            sOut[(ocl + 16) * 257 + (yb + r) * 16 + x0 + 1] = acc11[r];
        }
    }
    __syncthreads();
    {
        int m = t >> 1, half = t & 1;
        unsigned int dw[8];
#pragma unroll
        for (int j = 0; j < 8; ++j) {
            int oc0 = half * 16 + 2 * j;
            float v0 = fmaxf(sOut[oc0 * 257 + m] + b2[oc0], 0.0f);
            float v1 = fmaxf(sOut[(oc0 + 1) * 257 + m] + b2[oc0 + 1], 0.0f);
            dw[j] = (unsigned int)f2bf(v0) | ((unsigned int)f2bf(v1) << 16);
        }
        char* dst = (char*)c2b + ((size_t)b * 4096 + zo * 256 + m) * 64 + half * 32;
        *(int4*)dst        = int4{(int)dw[0], (int)dw[1], (int)dw[2], (int)dw[3]};
        *(int4*)(dst + 16) = int4{(int)dw[4], (int)dw[5], (int)dw[6], (int)dw[7]};
    }
}

// ---------------------------------------------------------------------------
// conv3 as implicit GEMM on MFMA 16x16x32 bf16.
// Block=(b,zo): 256 blocks x 512 thr. M=64 (8y x 8x), N=64 oc, K=27sh x 32c.
// 3-plane halo slab in LDS, x-parity-split voxels (64 B each):
//   u(kz,iy_st,ix_st) = (kz*17 + iy_st)*17 + (ix_st&1 ? 9 + ix_st/2 : ix_st/2)
// A-frag addr = u*64 + g*16 -> per-shift offset is a compile-time constant
// folded into the ds_read immediate; stride-1-in-x => conflict-floor b128.
// No barriers in the K-loop; weights from L2 (coalesced 1 KB/wave reads).
// ---------------------------------------------------------------------------
__global__ __launch_bounds__(512) void k_conv3_mfma(
        const unsigned short* __restrict__ c2b,
        const unsigned short* __restrict__ w3b,
        const float* __restrict__ b3,
        float* __restrict__ feat) {
    __shared__ __align__(16) char smem[55488];
    const int t = threadIdx.x;
    const int b = blockIdx.x >> 3;
    const int zo = blockIdx.x & 7;
    const int lane = t & 63;
    const int wid = t >> 6;                          // 8 waves

    // zero halo: per plane, row iy_st=0 (17 slots) + col ix_st=0 (16 rows)
    if (t < 396) {
        int p3 = t / 132, j = t % 132;
        int v = j >> 2, g = j & 3;
        int iy_st = (v < 17) ? 0 : (v - 16);
        int ix_st = (v < 17) ? v : 0;
        int ux = (ix_st & 1) ? 9 + (ix_st >> 1) : (ix_st >> 1);
        int u = (p3 * 17 + iy_st) * 17 + ux;
        *(int4*)(smem + u * 64 + g * 16) = int4{0, 0, 0, 0};
    }

    // stage 3 planes: 768 voxels x 4 chunks = 3072 chunks, 6 per thread
    const char* src = (const char*)c2b + (size_t)b * 262144;
#pragma unroll
    for (int r = 0; r < 6; ++r) {
        int i = r * 512 + t;
        int g = i & 3, vox = i >> 2;
        int kz = vox >> 8, pos = vox & 255;
        int iy = pos >> 4, ix = pos & 15;
        int iz = 2 * zo + kz - 1;                    // only -1 can be OOB
        int4 v = {0, 0, 0, 0};
        if (iz >= 0)
            v = *(const int4*)(src + ((size_t)(iz * 256 + pos)) * 64 + g * 16);
        int ix_st = ix + 1;
        int ux = (ix_st & 1) ? 9 + (ix_st >> 1) : (ix_st >> 1);
        int u = (kz * 17 + iy + 1) * 17 + ux;
        *(int4*)(smem + u * 64 + g * 16) = v;
    }
    __syncthreads();

    const int mt = wid >> 1;                         // M-tile 0..3
    const int ntp = wid & 1;                         // N-tile pair 0..1
    const int m = mt * 16 + (lane & 15);
    const int y = m >> 3, x = m & 7;
    const int g = lane >> 4;
    const int laneA = (34 * y + x) * 64 + g * 16;
    const char* wb_base = (const char*)w3b + (ntp * 32 + (lane & 15)) * 64 + g * 16;

    f32x4 acc0 = {0, 0, 0, 0}, acc1 = {0, 0, 0, 0};

#pragma unroll
    for (int sh = 0; sh < 27; ++sh) {
        const int kz = sh / 9, ky = (sh % 9) / 3, kx = sh % 3;
        const int uxc = (kx == 0) ? 0 : ((kx == 1) ? 9 : 1);
        const int aoff = (289 * kz + 17 * ky + uxc) * 64;
        bf16x8 A = *(const bf16x8*)(smem + laneA + aoff);
        const char* wb = wb_base + sh * 4096;
        bf16x8 B0 = *(const bf16x8*)wb;
        bf16x8 B1 = *(const bf16x8*)(wb + 1024);
        acc0 = __builtin_amdgcn_mfma_f32_16x16x32_bf16(A, B0, acc0, 0, 0, 0);
        acc1 = __builtin_amdgcn_mfma_f32_16x16x32_bf16(A, B1, acc1, 0, 0, 0);
    }

    // epilogue: transpose through LDS (slab dead), fp32 feat standard layout.
    __syncthreads();
    float* sOut = (float*)smem;                      // [64 oc][65]
    {
        int ocl = lane & 15;
        int mb = mt * 16 + (lane >> 4) * 4;
#pragma unroll
        for (int r = 0; r < 4; ++r) {
            sOut[(ntp * 32 + ocl) * 65 + mb + r]      = acc0[r];
            sOut[(ntp * 32 + 16 + ocl) * 65 + mb + r] = acc1[r];
        }
    }
    __syncthreads();
    {
        int oc = t >> 3, q = t & 7;
        float bb = b3[oc];
        float* dst = feat + (size_t)b * 32768 + oc * 512 + zo * 64 + q * 8;
#pragma unroll
        for (int k = 0; k < 8; ++k) {
            float v = sOut[oc * 65 + q * 8 + k] + bb;
            dst[k] = fmaxf(v, 0.0f);
        }
    }
}

// FC: out(32,128) = feat(32,32768) @ fc_w(128,32768)^T + fc_b. (unchanged)
__global__ void k_fc(const float* __restrict__ feat,
                     const float* __restrict__ fc_w,
                     const float* __restrict__ fc_b,
                     float* __restrict__ out) {
    __shared__ float lds[256 * 36];
    int fchunk = blockIdx.x & 127;
    int lg = blockIdx.x >> 7;
    int t = threadIdx.x;
    int f0 = fchunk * 256;
    for (int b = 0; b < 32; ++b)
        lds[t * 36 + b] = feat[b * 32768 + f0 + t];
    __syncthreads();

    int l = lg * 32 + (t >> 3);
    int bq = t & 7;
    const float* wrow = fc_w + l * 32768 + f0;
    float a0 = 0.f, a1 = 0.f, a2 = 0.f, a3 = 0.f;
    for (int f = 0; f < 256; ++f) {
        float wv = wrow[f];
        const float* p = &lds[f * 36 + bq * 4];
        a0 = fmaf(p[0], wv, a0);
        a1 = fmaf(p[1], wv, a1);
        a2 = fmaf(p[2], wv, a2);
        a3 = fmaf(p[3], wv, a3);
    }
    if (fchunk == 0) {
        float bb = fc_b[l];
        a0 += bb; a1 += bb; a2 += bb; a3 += bb;
    }
    int b0 = bq * 4;
    atomicAdd(&out[(b0 + 0) * 128 + l], a0);
    atomicAdd(&out[(b0 + 1) * 128 + l], a1);
    atomicAdd(&out[(b0 + 2) * 128 + l], a2);
    atomicAdd(&out[(b0 + 3) * 128 + l], a3);
}

extern "C" void kernel_launch(void* const* d_in, const int* in_sizes, int n_in,
                              void* d_out, int out_size, void* d_ws, size_t ws_size,
                              hipStream_t stream) {
    const float* coords = (const float*)d_in[0];
    const float* w1 = (const float*)d_in[1];
    const float* b1 = (const float*)d_in[2];
    const float* w2 = (const float*)d_in[3];
    const float* b2 = (const float*)d_in[4];
    const float* w3 = (const float*)d_in[5];
    const float* b3 = (const float*)d_in[6];
    const float* fc_w = (const float*)d_in[7];
    const float* fc_b = (const float*)d_in[8];

    unsigned char* grid_u8 = (unsigned char*)d_ws;
    unsigned short* w2b = (unsigned short*)((char*)d_ws + 65536);   // aliases grid
    unsigned short* w3b = (unsigned short*)((char*)d_ws + 131072);  // aliases grid
    unsigned short* c1b = (unsigned short*)((char*)d_ws + 8388608);
    unsigned short* c2b = (unsigned short*)((char*)d_ws + 75497472);
    float* feat = (float*)((char*)d_ws + 92274688);
    float* out = (float*)d_out;

    hipMemsetAsync(grid_u8, 0, 8388608, stream);
    hipMemsetAsync(out, 0, 32 * 128 * sizeof(float), stream);

    k_scatter<<<2048, 256, 0, stream>>>(coords, grid_u8);
    k_conv1<<<4096, 256, 0, stream>>>(grid_u8, w1, b1, c1b);
    k_wtrans<<<272, 256, 0, stream>>>(w2, w2b, w3, w3b);            // grid dead now
    k_conv2_mfma<<<512, 512, 0, stream>>>(c1b, w2b, b2, c2b);
    k_conv3_mfma<<<256, 512, 0, stream>>>(c2b, w3b, b3, feat);
    k_fc<<<512, 256, 0, stream>>>(feat, fc_w, fc_b, out);
}